// Round 7
// baseline (299.843 us; speedup 1.0000x reference)
//
#include <hip/hip_runtime.h>
#include <math.h>

#define TSTEPS 48
#define FEAT 60
#define BATCH 128
#define BLOCK 1024
#define TWO_PI_F 6.2831853071795864769f

// BLOCK=1024: 16 waves/block -> 4 waves/SIMD, 2 amps/thread.
// qubits: q0=l5 q1=r0 q2=l4 q3=l3 q4=l2 q5=l1 q6=l0 q7=w3 q8=w2 q9=w1 q10=w0
// L1 1q gates folded into embedding; L1 CRXs local. L2 q0..q6 local (CRX
// fused). L2 q7..q10 = fused 16x16 wave merge (coeffs in SGPRs), computed one
// step deferred inside the next body (off the recurrence path), single
// barrier per step; parity double-buffered exchange/reduction buffers.

struct Cf { float r, i; };
__device__ __forceinline__ Cf cmul(Cf a, Cf b){ return {a.r*b.r - a.i*b.i, a.r*b.i + a.i*b.r}; }
__device__ __forceinline__ Cf cadd(Cf a, Cf b){ return {a.r+b.r, a.i+b.i}; }
__device__ __forceinline__ void mm2(const Cf A[4], const Cf B[4], Cf D[4]) {
  D[0] = cadd(cmul(A[0],B[0]), cmul(A[1],B[2]));
  D[1] = cadd(cmul(A[0],B[1]), cmul(A[1],B[3]));
  D[2] = cadd(cmul(A[2],B[0]), cmul(A[3],B[2]));
  D[3] = cadd(cmul(A[2],B[1]), cmul(A[3],B[3]));
}

struct Mat { float4 r0, r1; };

__device__ __forceinline__ float rlane(float v, int l) {
  return __int_as_float(__builtin_amdgcn_readlane(__float_as_int(v), l));
}
__device__ __forceinline__ float rfl(float v) {
  return __int_as_float(__builtin_amdgcn_readfirstlane(__float_as_int(v)));
}

template<int CTRL>
__device__ __forceinline__ float dppf(float v) {
  return __int_as_float(__builtin_amdgcn_mov_dpp(__float_as_int(v), CTRL, 0xF, 0xF, true));
}

// xor-lane exchange. 1,2:quad_perm 4:reverse∘half_mirror 8:row_ror:8
// 16,32: ds_swizzle/permute via __shfl_xor
template<int M>
__device__ __forceinline__ float sx(float v) {
  if constexpr (M == 1)      return dppf<0xB1>(v);
  else if constexpr (M == 2) return dppf<0x4E>(v);
  else if constexpr (M == 4) return dppf<0x141>(dppf<0x1B>(v));
  else if constexpr (M == 8) return dppf<0x128>(v);
  else return __shfl_xor(v, M, 64);
}

__device__ __forceinline__ Cf csel(float4 v, int b) {
  return b ? Cf{v.z, v.w} : Cf{v.x, v.y};
}

__device__ __forceinline__ float4 rowsel(const float* M, int bit) {
  return bit ? make_float4(M[6],M[7],M[4],M[5])
             : make_float4(M[0],M[1],M[2],M[3]);
}

template<int MASK>
__device__ __forceinline__ void lgate(float2& a, float4 m) {
  float px = sx<MASK>(a.x), py = sx<MASK>(a.y);
  float ax = a.x, ay = a.y;
  a.x = m.x*ax - m.y*ay + m.z*px - m.w*py;
  a.y = m.x*ay + m.y*ax + m.z*py + m.w*px;
}

__device__ __forceinline__ void rgate(float2& A, float2& B, Mat M) {
  float2 A0 = A, B0 = B;
  A.x = M.r0.x*A0.x - M.r0.y*A0.y + M.r0.z*B0.x - M.r0.w*B0.y;
  A.y = M.r0.x*A0.y + M.r0.y*A0.x + M.r0.z*B0.y + M.r0.w*B0.x;
  B.x = M.r1.x*A0.x - M.r1.y*A0.y + M.r1.z*B0.x - M.r1.w*B0.y;
  B.y = M.r1.x*A0.y + M.r1.y*A0.x + M.r1.z*B0.y + M.r1.w*B0.x;
}

__device__ __forceinline__ void rxmix(float2& a0, float2& a1, float c, float s) {
  float n0x = c*a0.x + s*a1.y, n0y = c*a0.y - s*a1.x;
  float n1x = c*a1.x + s*a0.y, n1y = c*a1.y - s*a0.x;
  a0.x = n0x; a0.y = n0y; a1.x = n1x; a1.y = n1y;
}

template<int MASK>
__device__ __forceinline__ void rxs(float2& a, float c, float s) {
  float px = sx<MASK>(a.x), py = sx<MASK>(a.y);
  float ax = a.x, ay = a.y;
  a.x = c*ax + s*py;
  a.y = c*ay - s*px;
}

__global__ __launch_bounds__(BLOCK, 4)
void qrnn_kernel(const float* __restrict__ x, const float* __restrict__ hin,
                 const float* __restrict__ params, float* __restrict__ out) {
  const int b    = blockIdx.x;
  const int tid  = threadIdx.x;
  const int lane = tid & 63;
  const int w    = tid >> 6;                   // 0..15
  const int l5 = (lane>>5)&1, l4=(lane>>4)&1, l3=(lane>>3)&1,
            l2 = (lane>>2)&1, l1=(lane>>1)&1, l0=lane&1;

  __shared__ __align__(16) float matU[2][11][8];
  __shared__ __align__(16) float matVs[4][8];
  __shared__ float  xs[TSTEPS*FEAT];
  __shared__ float  pooled[TSTEPS][6];
  __shared__ float4 evis[TSTEPS][6];
  __shared__ __align__(16) float4 xb[2][1024];    // parity planes (a0,a1)
  __shared__ __align__(16) float wredT[2][8][16]; // [parity][slot][wave]
  __shared__ __align__(16) float sredT[2][16];    // [parity][wave]

  // ---- stage x ----
  for (int j = tid; j < TSTEPS*FEAT; j += BLOCK)
    xs[j] = x[(size_t)b*TSTEPS*FEAT + j];
  // ---- fused per-(layer,qubit) U = RZ*RY*RX ----
  if (tid < 22) {
    int l = tid / 11, k = tid % 11;
    int base = 37 * l;
    int off = (k < 5) ? (base + 3*k) : (base + 19 + 3*(k-5));
    float px = params[off], py = params[off+1], pz = params[off+2];
    float cx = cosf(0.5f*px), sxn = sinf(0.5f*px);
    float cy = cosf(0.5f*py), syn = sinf(0.5f*py);
    float cz = cosf(0.5f*pz), szn = sinf(0.5f*pz);
    Cf RX[4] = {{cx,0.f},{0.f,-sxn},{0.f,-sxn},{cx,0.f}};
    Cf RY[4] = {{cy,0.f},{-syn,0.f},{syn,0.f},{cy,0.f}};
    Cf RZ[4] = {{cz,-szn},{0.f,0.f},{0.f,0.f},{cz,szn}};
    Cf M[4], U[4];
    mm2(RY, RX, M);
    mm2(RZ, M,  U);
    float* d = &matU[l][k][0];
    d[0]=U[0].r; d[1]=U[0].i; d[2]=U[1].r; d[3]=U[1].i;
    d[4]=U[2].r; d[5]=U[2].i; d[6]=U[3].r; d[7]=U[3].i;
  }
  __syncthreads();
  if (tid < 4) {                                // V[i] = RX(th_L2,i)*U2[i+1]
    float th = params[37 + 15 + tid];
    float c = cosf(0.5f*th), s = sinf(0.5f*th);
    const float* Up = &matU[1][tid+1][0];
    Cf U00{Up[0],Up[1]}, U01{Up[2],Up[3]}, U10{Up[4],Up[5]}, U11{Up[6],Up[7]};
    Cf ms{0.f, -s};
    Cf V00 = cadd(Cf{c*U00.r, c*U00.i}, cmul(ms, U10));
    Cf V01 = cadd(Cf{c*U01.r, c*U01.i}, cmul(ms, U11));
    Cf V10 = cadd(cmul(ms, U00), Cf{c*U10.r, c*U10.i});
    Cf V11 = cadd(cmul(ms, U01), Cf{c*U11.r, c*U11.i});
    float* d = &matVs[tid][0];
    d[0]=V00.r; d[1]=V00.i; d[2]=V01.r; d[3]=V01.i;
    d[4]=V10.r; d[5]=V10.i; d[6]=V11.r; d[7]=V11.i;
  }
  for (int j = tid; j < TSTEPS*6; j += BLOCK) {
    int t = j / 6, k = j % 6;
    const float* xp = &xs[t*FEAT + k*10];
    float s = 0.f;
    #pragma unroll
    for (int f = 0; f < 10; ++f) s += xp[f];
    pooled[t][k] = s * 0.1f;
  }
  __syncthreads();
  for (int j = tid; j < TSTEPS*6; j += BLOCK) {
    int t = j / 6, k = j % 6;
    float mn = pooled[t][0], mx = pooled[t][0];
    #pragma unroll
    for (int v = 1; v < 6; ++v) { mn = fminf(mn, pooled[t][v]); mx = fmaxf(mx, pooled[t][v]); }
    float ang = TWO_PI_F * (pooled[t][k] - mn) / (mx - mn + 1e-8f);
    float c = __cosf(0.5f*ang), s = __sinf(0.5f*ang);
    const float* U = &matU[0][5+k][0];
    evis[t][k] = make_float4(U[0]*c + U[3]*s, U[1]*c - U[2]*s,
                             U[4]*c + U[7]*s, U[5]*c - U[6]*s);
  }

  // ---- per-thread loop-invariant gate data ----
  Mat Mq1;                                      // q1 reg-gate, ctrl q0=l5
  { const float* p = l5 ? &matVs[0][0] : &matU[1][1][0];
    Mq1.r0 = *(const float4*)p; Mq1.r1 = *(const float4*)(p+4); }
  float4 q0row  = rowsel(&matU[1][0][0], l5);
  float4 q2rowU = rowsel(&matU[1][2][0], l4);   // amp r=0
  float4 q2rowV = rowsel(&matVs[1][0],   l4);   // amp r=1 (ctrl q1=r0)
  float4 q3row  = rowsel(l4 ? &matVs[2][0] : &matU[1][3][0], l3);  // ctrl q2=l4
  float4 q4row  = rowsel(l3 ? &matVs[3][0] : &matU[1][4][0], l2);  // ctrl q3=l3
  float4 q5row  = rowsel(&matU[1][5][0], l1);
  float4 q6row  = rowsel(&matU[1][6][0], l0);
  float c1p, s1p, c2v, s2v, c3p, s3p, c4p, s4p;
  { float th = params[15]; float c = cosf(0.5f*th), s = sinf(0.5f*th);
    c1p = l5 ? c : 1.f; s1p = l5 ? s : 0.f; }   // CRX(q0,q1) ctrl l5
  { float th = params[16]; c2v = cosf(0.5f*th); s2v = sinf(0.5f*th); }
  { float th = params[17]; float c = cosf(0.5f*th), s = sinf(0.5f*th);
    c3p = l4 ? c : 1.f; s3p = l4 ? s : 0.f; }   // CRX(q2,q3) ctrl l4
  { float th = params[18]; float c = cosf(0.5f*th), s = sinf(0.5f*th);
    c4p = l3 ? c : 1.f; s4p = l3 ? s : 0.f; }   // CRX(q3,q4) ctrl l3
  // merge coefficients: 16x16 tensor row (q7..q10 on w3..w0), XOR-indexed,
  // wave-uniform -> forced to SGPRs via readfirstlane
  float dR[16], dI[16];
  { const int i3 = (w>>3)&1, i2 = (w>>2)&1, i1 = (w>>1)&1, i0 = w&1;
    const float* u7  = &matU[1][7][0];
    const float* u8  = &matU[1][8][0];
    const float* u9  = &matU[1][9][0];
    const float* u10 = &matU[1][10][0];
    #pragma unroll
    for (int k = 0; k < 16; ++k) {
      int j = w ^ k;
      int j3 = (j>>3)&1, j2 = (j>>2)&1, j1 = (j>>1)&1, j0 = j&1;
      Cf a7 {u7 [(i3*2+j3)*2], u7 [(i3*2+j3)*2+1]};
      Cf a8 {u8 [(i2*2+j2)*2], u8 [(i2*2+j2)*2+1]};
      Cf a9 {u9 [(i1*2+j1)*2], u9 [(i1*2+j1)*2+1]};
      Cf a10{u10[(i0*2+j0)*2], u10[(i0*2+j0)*2+1]};
      Cf c = cmul(cmul(a7, a8), cmul(a9, a10));
      dR[k] = rfl(c.r); dI[k] = rfl(c.i);
    }
  }
  const int lq = (lane < 5) ? lane : 0;
  float4 mH0 = *(const float4*)&matU[0][lq][0];
  float4 mH1 = *(const float4*)&matU[0][lq][4];
  float hreg = (lane < 5) ? hin[b*5 + lane] : 0.f;
  __syncthreads();

  #pragma unroll 1
  for (int t = 0; t < TSTEPS; ++t) {
    const int cb = t & 1;
    const int pb = cb ^ 1;

    // ==== stream B: 16x16 merge of step t-1 (independent of hreg chain) ====
    if (t > 0) {
      float2 n0{0,0}, n1{0,0};
      #pragma unroll
      for (int k = 0; k < 16; ++k) {
        float4 p = xb[pb][((w ^ k)<<6) + lane];
        n0.x += dR[k]*p.x - dI[k]*p.y; n0.y += dR[k]*p.y + dI[k]*p.x;
        n1.x += dR[k]*p.z - dI[k]*p.w; n1.y += dR[k]*p.w + dI[k]*p.z;
      }
      float S = (n0.x*n0.x + n0.y*n0.y) + (n1.x*n1.x + n1.y*n1.y);
      S += sx<1>(S);  S += sx<2>(S);  S += sx<4>(S);
      S += sx<8>(S);  S += sx<16>(S); S += sx<32>(S);
      if (lane == 0) sredT[pb][w] = S;
    }

    // ==== stream A: step t embed -> gates (hreg-dependent chain) ====
    float4 v5 = evis[t][0], v6 = evis[t][1], v7 = evis[t][2],
           v8 = evis[t][3], v9 = evis[t][4], v10 = evis[t][5];
    Cf Fv = csel(v7, (w>>3)&1);                 // q7 = w3
    Fv = cmul(Fv, csel(v8, (w>>2)&1));          // q8 = w2
    Fv = cmul(Fv, csel(v9, (w>>1)&1));          // q9 = w1
    Fv = cmul(Fv, csel(v10, w&1));              // q10 = w0
    Fv = cmul(Fv, csel(v5, l1));                // q5
    Fv = cmul(Fv, csel(v6, l0));                // q6

    float chh = __cosf(0.5f*hreg), shh = __sinf(0.5f*hreg);
    float e0r_ = mH0.x*chh + mH0.w*shh;
    float e0i_ = mH0.y*chh - mH0.z*shh;
    float e1r_ = mH1.x*chh + mH1.w*shh;
    float e1i_ = mH1.y*chh - mH1.z*shh;
    Cf Eq0, Eq2, Eq3, Eq4, E1[2];
    { float A=rlane(e0r_,0), B=rlane(e0i_,0), C=rlane(e1r_,0), D=rlane(e1i_,0);
      Eq0 = { l5 ? C : A, l5 ? D : B }; }
    { float A=rlane(e0r_,2), B=rlane(e0i_,2), C=rlane(e1r_,2), D=rlane(e1i_,2);
      Eq2 = { l4 ? C : A, l4 ? D : B }; }
    { float A=rlane(e0r_,3), B=rlane(e0i_,3), C=rlane(e1r_,3), D=rlane(e1i_,3);
      Eq3 = { l3 ? C : A, l3 ? D : B }; }
    { float A=rlane(e0r_,4), B=rlane(e0i_,4), C=rlane(e1r_,4), D=rlane(e1i_,4);
      Eq4 = { l2 ? C : A, l2 ? D : B }; }
    E1[0] = { rlane(e0r_,1), rlane(e0i_,1) };
    E1[1] = { rlane(e1r_,1), rlane(e1i_,1) };

    Cf F = cmul(cmul(Fv, Eq0), cmul(Eq2, cmul(Eq3, Eq4)));
    float2 a[2];
    { Cf A0 = cmul(F, E1[0]); a[0].x = A0.r; a[0].y = A0.i; }
    { Cf A1 = cmul(F, E1[1]); a[1].x = A1.r; a[1].y = A1.i; }

    // layer 1 CRXs (all local)
    rxmix(a[0], a[1], c1p, s1p);                // CRX(q0,q1): tgt r0
    rxs<16>(a[1], c2v, s2v);                    // CRX(q1,q2): ctrl r0, tgt l4
    rxs<8>(a[0], c3p, s3p);                     // CRX(q2,q3): ctrl l4 (DPP)
    rxs<8>(a[1], c3p, s3p);
    rxs<4>(a[0], c4p, s4p);                     // CRX(q3,q4): ctrl l3 (DPP)
    rxs<4>(a[1], c4p, s4p);

    // layer 2: q0..q6 local
    lgate<32>(a[0], q0row);  lgate<32>(a[1], q0row);
    rgate(a[0], a[1], Mq1);                     // q1 (+CRX c=q0)
    lgate<16>(a[0], q2rowU); lgate<16>(a[1], q2rowV);  // q2 (+CRX c=q1)
    lgate<8>(a[0], q3row);   lgate<8>(a[1], q3row);    // q3 (+CRX c=q2) DPP
    lgate<4>(a[0], q4row);   lgate<4>(a[1], q4row);    // q4 (+CRX c=q3) DPP
    lgate<2>(a[0], q5row);   lgate<2>(a[1], q5row);    // q5 DPP
    lgate<1>(a[0], q6row);   lgate<1>(a[1], q6row);    // q6 DPP

    // pre-merge expectations (exact for q0..q6 by unitarity of the merge)
    float p0 = a[0].x*a[0].x + a[0].y*a[0].y;
    float p1 = a[1].x*a[1].x + a[1].y*a[1].y;
    float P  = p0+p1;
    float Z1 = p0-p1;                           // q1 (r0)
    float T0,T1,T2,T3,T4,T5;
    { float xx=sx<1>(P);  T0=(lane&1) ? xx-P : P-xx; P+=xx;
      Z1+=sx<1>(Z1); }
    { float xx=sx<2>(P);  T1=(lane&2) ? xx-P : P-xx; P+=xx;
      Z1+=sx<2>(Z1); T0+=sx<2>(T0); }
    { float xx=sx<4>(P);  T2=(lane&4) ? xx-P : P-xx; P+=xx;
      Z1+=sx<4>(Z1); T0+=sx<4>(T0); T1+=sx<4>(T1); }
    { float xx=sx<8>(P);  T3=(lane&8) ? xx-P : P-xx; P+=xx;
      Z1+=sx<8>(Z1); T0+=sx<8>(T0); T1+=sx<8>(T1); T2+=sx<8>(T2); }
    { float xx=sx<16>(P); T4=(lane&16)? xx-P : P-xx; P+=xx;
      Z1+=sx<16>(Z1); T0+=sx<16>(T0); T1+=sx<16>(T1);
      T2+=sx<16>(T2); T3+=sx<16>(T3); }
    { float xx=sx<32>(P); T5=(lane&32)? xx-P : P-xx; P+=xx;
      Z1+=sx<32>(Z1); T0+=sx<32>(T0); T1+=sx<32>(T1);
      T2+=sx<32>(T2); T3+=sx<32>(T3); T4+=sx<32>(T4); }
    if (lane == 0) {
      wredT[cb][0][w]=Z1; wredT[cb][1][w]=T0; wredT[cb][2][w]=T1;
      wredT[cb][3][w]=T2; wredT[cb][4][w]=T3; wredT[cb][5][w]=T4;
      wredT[cb][6][w]=T5;
    }
    // publish pre-merge amps for step t's merge (consumed next iteration)
    xb[cb][(w<<6)+lane] = make_float4(a[0].x, a[0].y, a[1].x, a[1].y);

    __syncthreads();                            // ---- the ONE barrier ----

    // hidden update: q0->T5(6) q1->Z1(0) q2->T4(5) q3->T3(4) q4->T2(3)
    if (lane < 5) {
      int slot = (lane==0) ? 6 : (lane==1) ? 0 : (lane==2) ? 5 : (lane==3) ? 4 : 3;
      float4 A4 = *(const float4*)&wredT[cb][slot][0];
      float4 B4 = *(const float4*)&wredT[cb][slot][4];
      float4 C4 = *(const float4*)&wredT[cb][slot][8];
      float4 D4 = *(const float4*)&wredT[cb][slot][12];
      hreg = ((A4.x+A4.y)+(A4.z+A4.w)) + ((B4.x+B4.y)+(B4.z+B4.w))
           + ((C4.x+C4.y)+(C4.z+C4.w)) + ((D4.x+D4.y)+(D4.z+D4.w));
      if (t == TSTEPS-1 && w == 0)
        out[BATCH*TSTEPS*6 + b*5 + lane] = hreg;
    }
    // o0,o1 (step t): w0 lanes 5,6: q5->T1(2) q6->T0(1)
    if (w == 0 && (lane == 5 || lane == 6)) {
      int slot = (lane==5) ? 2 : 1;
      float4 A4 = *(const float4*)&wredT[cb][slot][0];
      float4 B4 = *(const float4*)&wredT[cb][slot][4];
      float4 C4 = *(const float4*)&wredT[cb][slot][8];
      float4 D4 = *(const float4*)&wredT[cb][slot][12];
      out[(size_t)b*TSTEPS*6 + t*6 + (lane-5)] =
          ((A4.x+A4.y)+(A4.z+A4.w)) + ((B4.x+B4.y)+(B4.z+B4.w))
        + ((C4.x+C4.y)+(C4.z+C4.w)) + ((D4.x+D4.y)+(D4.z+D4.w));
    }
    // o2..o5 (step t-1, deferred): w1 lanes 0..3: q7(w3) q8(w2) q9(w1) q10(w0)
    if (w == 1 && lane < 4 && t > 0) {
      float4 A4 = *(const float4*)&sredT[pb][0];
      float4 B4 = *(const float4*)&sredT[pb][4];
      float4 C4 = *(const float4*)&sredT[pb][8];
      float4 D4 = *(const float4*)&sredT[pb][12];
      float z;
      if (lane == 0)       // q7: wave bit3
        z = ((A4.x+A4.y+A4.z+A4.w) + (B4.x+B4.y+B4.z+B4.w))
          - ((C4.x+C4.y+C4.z+C4.w) + (D4.x+D4.y+D4.z+D4.w));
      else if (lane == 1)  // q8: wave bit2
        z = ((A4.x+A4.y+A4.z+A4.w) - (B4.x+B4.y+B4.z+B4.w))
          + ((C4.x+C4.y+C4.z+C4.w) - (D4.x+D4.y+D4.z+D4.w));
      else if (lane == 2)  // q9: wave bit1
        z = ((A4.x+A4.y) - (A4.z+A4.w)) + ((B4.x+B4.y) - (B4.z+B4.w))
          + ((C4.x+C4.y) - (C4.z+C4.w)) + ((D4.x+D4.y) - (D4.z+D4.w));
      else                 // q10: wave bit0
        z = (A4.x-A4.y+A4.z-A4.w) + (B4.x-B4.y+B4.z-B4.w)
          + (C4.x-C4.y+C4.z-C4.w) + (D4.x-D4.y+D4.z-D4.w);
      out[(size_t)b*TSTEPS*6 + (t-1)*6 + 2 + lane] = z;
    }
  }

  // ---- tail: merge of t=47 and its o2..o5 ----
  {
    const int pb = (TSTEPS-1) & 1;   // = 1
    float2 n0{0,0}, n1{0,0};
    #pragma unroll
    for (int k = 0; k < 16; ++k) {
      float4 p = xb[pb][((w ^ k)<<6) + lane];
      n0.x += dR[k]*p.x - dI[k]*p.y; n0.y += dR[k]*p.y + dI[k]*p.x;
      n1.x += dR[k]*p.z - dI[k]*p.w; n1.y += dR[k]*p.w + dI[k]*p.z;
    }
    float S = (n0.x*n0.x + n0.y*n0.y) + (n1.x*n1.x + n1.y*n1.y);
    S += sx<1>(S);  S += sx<2>(S);  S += sx<4>(S);
    S += sx<8>(S);  S += sx<16>(S); S += sx<32>(S);
    if (lane == 0) sredT[pb][w] = S;
    __syncthreads();
    if (w == 1 && lane < 4) {
      float4 A4 = *(const float4*)&sredT[pb][0];
      float4 B4 = *(const float4*)&sredT[pb][4];
      float4 C4 = *(const float4*)&sredT[pb][8];
      float4 D4 = *(const float4*)&sredT[pb][12];
      float z;
      if (lane == 0)
        z = ((A4.x+A4.y+A4.z+A4.w) + (B4.x+B4.y+B4.z+B4.w))
          - ((C4.x+C4.y+C4.z+C4.w) + (D4.x+D4.y+D4.z+D4.w));
      else if (lane == 1)
        z = ((A4.x+A4.y+A4.z+A4.w) - (B4.x+B4.y+B4.z+B4.w))
          + ((C4.x+C4.y+C4.z+C4.w) - (D4.x+D4.y+D4.z+D4.w));
      else if (lane == 2)
        z = ((A4.x+A4.y) - (A4.z+A4.w)) + ((B4.x+B4.y) - (B4.z+B4.w))
          + ((C4.x+C4.y) - (C4.z+C4.w)) + ((D4.x+D4.y) - (D4.z+D4.w));
      else
        z = (A4.x-A4.y+A4.z-A4.w) + (B4.x-B4.y+B4.z-B4.w)
          + (C4.x-C4.y+C4.z-C4.w) + (D4.x-D4.y+D4.z-D4.w);
      out[(size_t)b*TSTEPS*6 + (TSTEPS-1)*6 + 2 + lane] = z;
    }
  }
}

extern "C" void kernel_launch(void* const* d_in, const int* in_sizes, int n_in,
                              void* d_out, int out_size, void* d_ws, size_t ws_size,
                              hipStream_t stream) {
  const float* x      = (const float*)d_in[0];
  const float* hidden = (const float*)d_in[1];
  const float* params = (const float*)d_in[2];
  float* out          = (float*)d_out;
  qrnn_kernel<<<dim3(BATCH), dim3(BLOCK), 0, stream>>>(x, hidden, params, out);
}

// Round 8
// 100.821 us; speedup vs baseline: 2.9740x; 2.9740x over previous
//
#include <hip/hip_runtime.h>
#include <math.h>

#define TSTEPS 48
#define FEAT 60
#define BATCH 128
#define BLOCK 256
#define TWO_PI_F 6.2831853071795864769f

// Key structure (exact): CRX gates only couple hidden qubits q0..q4. Visible
// qubits q5..q10 stay in product form for the whole circuit. So:
//  - outputs[b,t,:] (visible <Z>) = pure function of x[b,t] -> parallel
//    precompute: z = |v0|^2-|v1|^2 of W*(cos,- i sin), W = U2*U1 fused.
//  - the recurrence is a 5-qubit (32-amp) sim: one amp per lane (lanes 32-63
//    mirror), gates via DPP/shuffle, NO LDS, NO barriers, single wave.
// Wave 0: recurrence (writes hidden_final). Wave 1: visible precompute.
// Qubit->lane-bit map: q0=bit4 q1=bit3 q2=bit2 q3=bit1 q4=bit0.

struct Cf { float r, i; };
__device__ __forceinline__ Cf cmul(Cf a, Cf b){ return {a.r*b.r - a.i*b.i, a.r*b.i + a.i*b.r}; }
__device__ __forceinline__ void mm2(const Cf A[4], const Cf B[4], Cf D[4]) {
  D[0] = {A[0].r*B[0].r - A[0].i*B[0].i + A[1].r*B[2].r - A[1].i*B[2].i,
          A[0].r*B[0].i + A[0].i*B[0].r + A[1].r*B[2].i + A[1].i*B[2].r};
  D[1] = {A[0].r*B[1].r - A[0].i*B[1].i + A[1].r*B[3].r - A[1].i*B[3].i,
          A[0].r*B[1].i + A[0].i*B[1].r + A[1].r*B[3].i + A[1].i*B[3].r};
  D[2] = {A[2].r*B[0].r - A[2].i*B[0].i + A[3].r*B[2].r - A[3].i*B[2].i,
          A[2].r*B[0].i + A[2].i*B[0].r + A[3].r*B[2].i + A[3].i*B[2].r};
  D[3] = {A[2].r*B[1].r - A[2].i*B[1].i + A[3].r*B[3].r - A[3].i*B[3].i,
          A[2].r*B[1].i + A[2].i*B[1].r + A[3].r*B[3].i + A[3].i*B[3].r};
}

// fused U = RZ * RY * RX from 3 consecutive params
__device__ __forceinline__ void fusedU(const float* p, Cf U[4]) {
  float cx = cosf(0.5f*p[0]), sxn = sinf(0.5f*p[0]);
  float cy = cosf(0.5f*p[1]), syn = sinf(0.5f*p[1]);
  float cz = cosf(0.5f*p[2]), szn = sinf(0.5f*p[2]);
  Cf RX[4] = {{cx,0.f},{0.f,-sxn},{0.f,-sxn},{cx,0.f}};
  Cf RY[4] = {{cy,0.f},{-syn,0.f},{syn,0.f},{cy,0.f}};
  Cf RZ[4] = {{cz,-szn},{0.f,0.f},{0.f,0.f},{cz,szn}};
  Cf M[4];
  mm2(RY, RX, M);
  mm2(RZ, M, U);
}

template<int CTRL>
__device__ __forceinline__ float dppf(float v) {
  return __int_as_float(__builtin_amdgcn_mov_dpp(__float_as_int(v), CTRL, 0xF, 0xF, true));
}

// xor-lane exchange: 1,2 quad_perm; 4 = reverse∘half_mirror; 8 = row_ror:8;
// 16 via ds shuffle
template<int M>
__device__ __forceinline__ float sx(float v) {
  if constexpr (M == 1)      return dppf<0xB1>(v);
  else if constexpr (M == 2) return dppf<0x4E>(v);
  else if constexpr (M == 4) return dppf<0x141>(dppf<0x1B>(v));
  else if constexpr (M == 8) return dppf<0x128>(v);
  else return __shfl_xor(v, M, 64);
}

// 1q gate on lane-bit MASK; m = this lane's row (m.xy * a + m.zw * partner)
template<int MASK>
__device__ __forceinline__ void lgate(float2& a, float4 m) {
  float px = sx<MASK>(a.x), py = sx<MASK>(a.y);
  float ax = a.x, ay = a.y;
  a.x = m.x*ax - m.y*ay + m.z*px - m.w*py;
  a.y = m.x*ay + m.y*ax + m.z*py + m.w*px;
}

// (controlled-)RX across lane-bit MASK with per-lane-blended c,s
// (ctrl=0 lanes pass c=1,s=0): a' = c*a - i*s*partner
template<int MASK>
__device__ __forceinline__ void rxs(float2& a, float c, float s) {
  float px = sx<MASK>(a.x), py = sx<MASK>(a.y);
  float ax = a.x, ay = a.y;
  a.x = c*ax + s*py;
  a.y = c*ay - s*px;
}

__global__ __launch_bounds__(BLOCK)
void qrnn_kernel(const float* __restrict__ x, const float* __restrict__ hin,
                 const float* __restrict__ params, float* __restrict__ out) {
  const int b    = blockIdx.x;
  const int tid  = threadIdx.x;
  const int lane = tid & 63;
  const int w    = tid >> 6;

  if (w == 0) {
    // ================= hidden recurrence (single wave, no LDS) =============
    // per-lane loop-invariant rows
    float4 embR[5];   // L1 fused row for embedding e-vector
    float4 g2R[5];    // L2 fused 1q gate row (lgate form)
    #pragma unroll
    for (int q = 0; q < 5; ++q) {
      const int bit = (lane >> (4-q)) & 1;
      Cf U[4];
      fusedU(params + 3*q, U);               // layer 1, hidden qubit q
      embR[q] = bit ? make_float4(U[2].r, U[2].i, U[3].r, U[3].i)
                    : make_float4(U[0].r, U[0].i, U[1].r, U[1].i);
      fusedU(params + 37 + 3*q, U);          // layer 2, hidden qubit q
      g2R[q] = bit ? make_float4(U[3].r, U[3].i, U[2].r, U[2].i)
                   : make_float4(U[0].r, U[0].i, U[1].r, U[1].i);
    }
    // CRX trig, blended by this lane's control bit (q_i = bit 4-i)
    float c1[4], s1[4], c2[4], s2[4];
    #pragma unroll
    for (int i = 0; i < 4; ++i) {
      const int ctrl = (lane >> (4-i)) & 1;
      float t1 = params[15+i], t2 = params[52+i];
      c1[i] = ctrl ? cosf(0.5f*t1) : 1.f; s1[i] = ctrl ? sinf(0.5f*t1) : 0.f;
      c2[i] = ctrl ? cosf(0.5f*t2) : 1.f; s2[i] = ctrl ? sinf(0.5f*t2) : 0.f;
    }
    const float* hp = hin + b*5;
    float z0 = hp[0], z1 = hp[1], z2 = hp[2], z3 = hp[3], z4 = hp[4];

    #pragma unroll 1
    for (int t = 0; t < TSTEPS; ++t) {
      // trig of the 5 hidden angles (replicated in every lane — no broadcast)
      float cc0 = __cosf(0.5f*z0), ss0 = __sinf(0.5f*z0);
      float cc1 = __cosf(0.5f*z1), ss1 = __sinf(0.5f*z1);
      float cc2 = __cosf(0.5f*z2), ss2 = __sinf(0.5f*z2);
      float cc3 = __cosf(0.5f*z3), ss3 = __sinf(0.5f*z3);
      float cc4 = __cosf(0.5f*z4), ss4 = __sinf(0.5f*z4);
      // e_q = (L1 row)·(cos, -i sin); amp = product over qubits
      Cf e0{embR[0].x*cc0 + embR[0].w*ss0, embR[0].y*cc0 - embR[0].z*ss0};
      Cf e1{embR[1].x*cc1 + embR[1].w*ss1, embR[1].y*cc1 - embR[1].z*ss1};
      Cf e2{embR[2].x*cc2 + embR[2].w*ss2, embR[2].y*cc2 - embR[2].z*ss2};
      Cf e3{embR[3].x*cc3 + embR[3].w*ss3, embR[3].y*cc3 - embR[3].z*ss3};
      Cf e4{embR[4].x*cc4 + embR[4].w*ss4, embR[4].y*cc4 - embR[4].z*ss4};
      Cf A = cmul(cmul(e0, e1), cmul(cmul(e2, e3), e4));
      float2 a{A.r, A.i};

      // layer 1 CRX chain (targets q1..q4 -> masks 8,4,2,1)
      rxs<8>(a, c1[0], s1[0]);
      rxs<4>(a, c1[1], s1[1]);
      rxs<2>(a, c1[2], s1[2]);
      rxs<1>(a, c1[3], s1[3]);
      // layer 2 fused 1q gates (q0..q4 -> masks 16,8,4,2,1)
      lgate<16>(a, g2R[0]);
      lgate<8> (a, g2R[1]);
      lgate<4> (a, g2R[2]);
      lgate<2> (a, g2R[3]);
      lgate<1> (a, g2R[4]);
      // layer 2 CRX chain
      rxs<8>(a, c2[0], s2[0]);
      rxs<4>(a, c2[1], s2[1]);
      rxs<2>(a, c2[2], s2[2]);
      rxs<1>(a, c2[3], s2[3]);

      // <Z_q> via signed butterfly (T values end up replicated in all lanes)
      float P = a.x*a.x + a.y*a.y;
      float T1, T2, T4, T8, T16;
      { float xx = sx<1>(P);  T1  = (lane&1) ? xx-P : P-xx; P += xx; }
      { float xx = sx<2>(P);  T2  = (lane&2) ? xx-P : P-xx; P += xx;
        T1 += sx<2>(T1); }
      { float xx = sx<4>(P);  T4  = (lane&4) ? xx-P : P-xx; P += xx;
        T1 += sx<4>(T1); T2 += sx<4>(T2); }
      { float xx = sx<8>(P);  T8  = (lane&8) ? xx-P : P-xx; P += xx;
        T1 += sx<8>(T1); T2 += sx<8>(T2); T4 += sx<8>(T4); }
      { float xx = sx<16>(P); T16 = (lane&16)? xx-P : P-xx; P += xx;
        T1 += sx<16>(T1); T2 += sx<16>(T2); T4 += sx<16>(T4); T8 += sx<16>(T8); }
      z0 = T16; z1 = T8; z2 = T4; z3 = T2; z4 = T1;
    }
    if (lane < 5) {
      float hv = (lane==0) ? z0 : (lane==1) ? z1 : (lane==2) ? z2
               : (lane==3) ? z3 : z4;
      out[BATCH*TSTEPS*6 + b*5 + lane] = hv;
    }
  } else if (w == 1) {
    // ================= visible outputs (no recurrence) =====================
    const int t = lane;                      // lanes 0..47 handle a timestep
    if (t < TSTEPS) {
      const float* xp = x + (size_t)b*(TSTEPS*FEAT) + t*FEAT;
      float pooled[6];
      #pragma unroll
      for (int k = 0; k < 6; ++k) {
        float s = 0.f;
        #pragma unroll
        for (int f = 0; f < 10; ++f) s += xp[k*10 + f];
        pooled[k] = s * 0.1f;
      }
      float mn = pooled[0], mx = pooled[0];
      #pragma unroll
      for (int v = 1; v < 6; ++v) {
        mn = fminf(mn, pooled[v]); mx = fmaxf(mx, pooled[v]);
      }
      float* op = out + (size_t)b*(TSTEPS*6) + t*6;
      #pragma unroll
      for (int k = 0; k < 6; ++k) {
        Cf U1[4], U2[4], W[4];
        fusedU(params + 19 + 3*k, U1);       // layer 1, visible qubit k
        fusedU(params + 56 + 3*k, U2);       // layer 2, visible qubit k
        mm2(U2, U1, W);                      // W = U2*U1 (RX applied first)
        float ang = TWO_PI_F * (pooled[k] - mn) / (mx - mn + 1e-8f);
        float ch = __cosf(0.5f*ang), sh = __sinf(0.5f*ang);
        // v = W * (ch, -i sh)
        float v0r = W[0].r*ch + W[1].i*sh, v0i = W[0].i*ch - W[1].r*sh;
        float v1r = W[2].r*ch + W[3].i*sh, v1i = W[2].i*ch - W[3].r*sh;
        op[k] = (v0r*v0r + v0i*v0i) - (v1r*v1r + v1i*v1i);
      }
    }
  }
  // waves 2,3: nothing (exit immediately)
}

extern "C" void kernel_launch(void* const* d_in, const int* in_sizes, int n_in,
                              void* d_out, int out_size, void* d_ws, size_t ws_size,
                              hipStream_t stream) {
  const float* x      = (const float*)d_in[0];
  const float* hidden = (const float*)d_in[1];
  const float* params = (const float*)d_in[2];
  float* out          = (float*)d_out;
  qrnn_kernel<<<dim3(BATCH), dim3(BLOCK), 0, stream>>>(x, hidden, params, out);
}